// Round 7
// baseline (480.940 us; speedup 1.0000x reference)
//
#include <hip/hip_runtime.h>
#include <hip/hip_bf16.h>
#include <stdint.h>

// Problem dims (fixed by the reference)
constexpr int kB = 32;
constexpr int kS = 1024;
constexpr int kDin = 1024;
constexpr int kDout = 4096;
constexpr int kRank = 16;
constexpr int kNAdapt = 8;
constexpr int kM = kB * kS;     // 32768 rows
constexpr float kScale = 2.0f;  // alpha/rank = 32/16

typedef __attribute__((ext_vector_type(4))) float f32x4;
typedef __attribute__((ext_vector_type(8))) short s16x8;
typedef __attribute__((ext_vector_type(8))) unsigned short u16x8;
typedef __attribute__((ext_vector_type(4))) unsigned short u16x4;

__device__ __forceinline__ unsigned short f2bf(float f) {
  union { float f; uint32_t u; } x; x.f = f;
  uint32_t u = x.u;
  u += 0x7fffu + ((u >> 16) & 1u);   // round-to-nearest-even
  return (unsigned short)(u >> 16);
}

// ---------- Kernel 1: cast hidden_states f32 -> bf16 (vectorized 8/thread) ----------
__global__ void cast_h_kernel(const float* __restrict__ h, unsigned short* __restrict__ out) {
  size_t i = (size_t)blockIdx.x * blockDim.x + threadIdx.x;
  const f32x4* src = reinterpret_cast<const f32x4*>(h) + i * 2;
  f32x4 v0 = src[0], v1 = src[1];
  u16x8 r;
  r[0] = f2bf(v0[0]); r[1] = f2bf(v0[1]); r[2] = f2bf(v0[2]); r[3] = f2bf(v0[3]);
  r[4] = f2bf(v1[0]); r[5] = f2bf(v1[1]); r[6] = f2bf(v1[2]); r[7] = f2bf(v1[3]);
  *reinterpret_cast<u16x8*>(out + i * 8) = r;
}

// ---------- Kernel 2: LDS-tiled transpose + rank-16 update (R2, verified) ----------
__global__ __launch_bounds__(256) void build_weff_kernel(
    const float* __restrict__ W,
    const float* __restrict__ la,
    const float* __restrict__ lb,
    unsigned short* __restrict__ weff) {
  __shared__ float Wt[64][68];
  __shared__ float At[64][20];
  __shared__ float Bt[16][68];
  int bid = blockIdx.x;
  int e = bid & 7;
  int rem = bid >> 3;
  int dt = rem >> 6;
  int ot = rem & 63;
  int d0 = dt * 64, o0 = ot * 64;
  int t = threadIdx.x;
  {
    int r = t >> 4;
    int c = (t & 15) * 4;
    const float* wp = W + (size_t)(d0 + r) * kDout + o0 + c;
#pragma unroll
    for (int p = 0; p < 4; ++p) {
      f32x4 v = *reinterpret_cast<const f32x4*>(wp + (size_t)p * 16 * kDout);
      *reinterpret_cast<f32x4*>(&Wt[p * 16 + r][c]) = v;
    }
  }
  {
    int d = t >> 2, r4 = (t & 3) * 4;
    f32x4 v = *reinterpret_cast<const f32x4*>(la + ((size_t)e * kDin + d0 + d) * kRank + r4);
    *reinterpret_cast<f32x4*>(&At[d][r4]) = v;
  }
  {
    int r = t >> 4, c = (t & 15) * 4;
    f32x4 v = *reinterpret_cast<const f32x4*>(lb + ((size_t)e * kRank + r) * kDout + o0 + c);
    *reinterpret_cast<f32x4*>(&Bt[r][c]) = v;
  }
  __syncthreads();
  int ol_base = t >> 4;
  int dl = (t & 15) * 4;
  f32x4 areg[4][4];
#pragma unroll
  for (int j = 0; j < 4; ++j)
#pragma unroll
    for (int q = 0; q < 4; ++q)
      areg[j][q] = *reinterpret_cast<const f32x4*>(&At[dl + j][q * 4]);
#pragma unroll
  for (int p = 0; p < 4; ++p) {
    int ol = p * 16 + ol_base;
    float bv[kRank];
#pragma unroll
    for (int r = 0; r < kRank; ++r) bv[r] = Bt[r][ol];
    u16x4 r4;
#pragma unroll
    for (int j = 0; j < 4; ++j) {
      float acc = 0.f;
#pragma unroll
      for (int q = 0; q < 4; ++q)
        acc += areg[j][q][0] * bv[q * 4 + 0] + areg[j][q][1] * bv[q * 4 + 1] +
               areg[j][q][2] * bv[q * 4 + 2] + areg[j][q][3] * bv[q * 4 + 3];
      r4[j] = f2bf(Wt[dl + j][ol] + kScale * acc);
    }
    *reinterpret_cast<u16x4*>(weff + ((size_t)e * kDout + o0 + ol) * kDin + d0 + dl) = r4;
  }
}

// ---------- Kernel 3: 256x256 counted-vmcnt 2-phase grouped GEMM ----------
// Per K-tile: VMC(8) -> barrier -> {24 ds_read + 64 MFMA, compiler-scheduled,
// NO intra-tile fences} -> barrier -> stage L(kt+2). A,B double-buffered.
// L(kt) issued end of iter kt-2, gated top of iter kt (full-tile distance).
constexpr int BM = 256, BN = 256, BK = 64;
constexpr int MT2 = kM / BM;      // 128
constexpr int NT2 = kDout / BN;   // 16
constexpr int NWG2 = MT2 * NT2;   // 2048

__device__ __forceinline__ void gload16(const unsigned short* g, unsigned short* l) {
  __builtin_amdgcn_global_load_lds((const __attribute__((address_space(1))) void*)g,
                                   (__attribute__((address_space(3))) void*)l, 16, 0, 0);
}

// LDS elem layout: A slot s in {0,1}: s*16384 + instr*4096 + t*8
//                  B slot s in {0,1}: 32768 + s*16384 + instr*4096 + t*8
// logical (row r, elem c) lives at r*64 + (c ^ ((r&7)<<3)); source pre-swizzled.
#define STG_A(s, kk) do { \
  gload16(gA + (size_t)0 * kDin + (kk) * 64, ldst + (s) * 16384); \
  gload16(gA + (size_t)64 * kDin + (kk) * 64, ldst + (s) * 16384 + 4096); \
  gload16(gA + (size_t)128 * kDin + (kk) * 64, ldst + (s) * 16384 + 8192); \
  gload16(gA + (size_t)192 * kDin + (kk) * 64, ldst + (s) * 16384 + 12288); \
} while (0)
#define STG_B(s, kk) do { \
  gload16(gB + (size_t)0 * kDin + (kk) * 64, ldst + 32768 + (s) * 16384); \
  gload16(gB + (size_t)64 * kDin + (kk) * 64, ldst + 32768 + (s) * 16384 + 4096); \
  gload16(gB + (size_t)128 * kDin + (kk) * 64, ldst + 32768 + (s) * 16384 + 8192); \
  gload16(gB + (size_t)192 * kDin + (kk) * 64, ldst + 32768 + (s) * 16384 + 12288); \
} while (0)

#define RD_A(mh, s) do { _Pragma("unroll") for (int ii = 0; ii < 4; ++ii) { \
  a[ii][0] = *(const s16x8*)&lds[(s) * 16384 + aRow + ((mh) * 4 + ii) * 1024 + e0]; \
  a[ii][1] = *(const s16x8*)&lds[(s) * 16384 + aRow + ((mh) * 4 + ii) * 1024 + e1]; } } while (0)
#define RD_B(nh, breg, s) do { _Pragma("unroll") for (int jj = 0; jj < 2; ++jj) { \
  breg[jj][0] = *(const s16x8*)&lds[32768 + (s) * 16384 + bRow + ((nh) * 2 + jj) * 1024 + e0]; \
  breg[jj][1] = *(const s16x8*)&lds[32768 + (s) * 16384 + bRow + ((nh) * 2 + jj) * 1024 + e1]; } } while (0)

#define MMQ(mh, nh, breg) do { \
  _Pragma("unroll") for (int ii = 0; ii < 4; ++ii) \
  _Pragma("unroll") for (int jj = 0; jj < 2; ++jj) { \
    acc[(mh) * 4 + ii][(nh) * 2 + jj] = __builtin_amdgcn_mfma_f32_16x16x32_bf16( \
        a[ii][0], breg[jj][0], acc[(mh) * 4 + ii][(nh) * 2 + jj], 0, 0, 0); \
    acc[(mh) * 4 + ii][(nh) * 2 + jj] = __builtin_amdgcn_mfma_f32_16x16x32_bf16( \
        a[ii][1], breg[jj][1], acc[(mh) * 4 + ii][(nh) * 2 + jj], 0, 0, 0); } \
} while (0)

#define VMC(n) asm volatile("s_waitcnt vmcnt(" #n ")" ::: "memory")

__global__ __launch_bounds__(512, 2) void gemm256_kernel(
    const unsigned short* __restrict__ Ab,    // [M][K] bf16
    const unsigned short* __restrict__ Weff,  // [NA][N][K] bf16
    const float* __restrict__ bias,
    const int* __restrict__ aids,
    float* __restrict__ out) {
  __shared__ unsigned short lds[65536];   // 128 KiB: A[2] + B[2] slots
  int bid = blockIdx.x;
  int swz = (bid & 7) * (NWG2 / 8) + (bid >> 3);   // XCD-aware, bijective
  int mt = swz >> 4, nt = swz & 15;
  int aid = aids[mt >> 2];   // BM=256 divides S=1024: one sample per M-tile
  const unsigned short* Aptr = Ab + (size_t)mt * BM * kDin;
  const unsigned short* Bptr = Weff + ((size_t)aid * kDout + (size_t)nt * BN) * kDin;

  int t = threadIdx.x;
  int l = t & 63;
  int w = t >> 6;
  int wm = w >> 2;   // 0..1 (M)
  int wn = w & 3;    // 0..3 (N)

  // staging: thread t covers row t>>3 (per 64-row chunk), 16B col (t&7);
  // global source col pre-swizzled so LDS stays linear (rule #21)
  int srcColEl = ((t & 7) * 8) ^ (((t >> 3) & 7) << 3);
  const unsigned short* gA = Aptr + (size_t)(t >> 3) * kDin + srcColEl;
  const unsigned short* gB = Bptr + (size_t)(t >> 3) * kDin + srcColEl;
  unsigned short* ldst = lds + t * 8;

  // fragment-read addressing (element units)
  int xmEl = (l & 7) << 3;
  int e0 = (((l >> 4) * 8) ^ xmEl);
  int e1 = e0 ^ 32;
  int aRow = (wm * 128 + (l & 15)) * 64;
  int bRow = (wn * 64 + (l & 15)) * 64;

  f32x4 acc[8][4];
#pragma unroll
  for (int m = 0; m < 8; ++m)
#pragma unroll
    for (int n = 0; n < 4; ++n) acc[m][n] = f32x4{0.f, 0.f, 0.f, 0.f};
  s16x8 a[4][2], b0[2][2], b1[2][2];

  // prologue: L(0) = {A,B slot0}, L(1) = {A,B slot1}; FIFO oldest 8 = L(0)
  STG_A(0, 0); STG_B(0, 0);
  STG_A(1, 1); STG_B(1, 1);

#pragma unroll
  for (int kt = 0; kt < 16; ++kt) {
    const int s = kt & 1;
    if (kt < 15) { VMC(8); } else { VMC(0); }   // L(kt) landed; L(kt+1) may fly
    __builtin_amdgcn_s_barrier();
    __builtin_amdgcn_sched_barrier(0);
    // ---- intra-tile: NO fences; compiler interleaves ds_read/MFMA ----
    RD_A(0, s);
    RD_B(0, b0, s); RD_B(1, b1, s);
    MMQ(0, 0, b0); MMQ(0, 1, b1);
    RD_A(1, s);
    MMQ(1, 0, b0); MMQ(1, 1, b1);
    __builtin_amdgcn_sched_barrier(0);
    __builtin_amdgcn_s_barrier();
    if (kt < 14) { STG_A(s, kt + 2); STG_B(s, kt + 2); }   // overwrite slot kt%2
  }

  // epilogue: C/D layout col = lane&15, row = (lane>>4)*4 + reg
  size_t row0 = (size_t)mt * BM + wm * 128 + (l >> 4) * 4;
  int col0 = nt * BN + wn * 64 + (l & 15);
#pragma unroll
  for (int nf = 0; nf < 4; ++nf) {
    float bv = bias[col0 + nf * 16];
#pragma unroll
    for (int mf = 0; mf < 8; ++mf) {
#pragma unroll
      for (int j = 0; j < 4; ++j)
        out[(row0 + mf * 16 + j) * kDout + col0 + nf * 16] = acc[mf][nf][j] + bv;
    }
  }
}

extern "C" void kernel_launch(void* const* d_in, const int* in_sizes, int n_in,
                              void* d_out, int out_size, void* d_ws, size_t ws_size,
                              hipStream_t stream) {
  const float* h    = (const float*)d_in[0];   // [32,1024,1024] f32
  const int*   aids = (const int*)d_in[1];     // [32] i32
  const float* W    = (const float*)d_in[2];   // [1024,4096] f32
  const float* bias = (const float*)d_in[3];   // [4096] f32
  const float* la   = (const float*)d_in[4];   // [8,1024,16] f32
  const float* lb   = (const float*)d_in[5];   // [8,16,4096] f32
  float* out = (float*)d_out;                  // [32,1024,4096] f32

  unsigned short* Abf  = (unsigned short*)d_ws;
  unsigned short* Weff = Abf + (size_t)kM * kDin;

  cast_h_kernel<<<(kM * (size_t)kDin / 8) / 256, 256, 0, stream>>>(h, Abf);
  build_weff_kernel<<<kNAdapt * (kDin / 64) * (kDout / 64), 256, 0, stream>>>(W, la, lb, Weff);
  gemm256_kernel<<<NWG2, 512, 0, stream>>>(Abf, Weff, bias, aids, out);
}

// Round 8
// 427.676 us; speedup vs baseline: 1.1245x; 1.1245x over previous
//
#include <hip/hip_runtime.h>
#include <hip/hip_bf16.h>
#include <stdint.h>

// Problem dims (fixed by the reference)
constexpr int kB = 32;
constexpr int kS = 1024;
constexpr int kDin = 1024;
constexpr int kDout = 4096;
constexpr int kRank = 16;
constexpr int kNAdapt = 8;
constexpr int kM = kB * kS;     // 32768 rows
constexpr float kScale = 2.0f;  // alpha/rank = 32/16

typedef __attribute__((ext_vector_type(4))) float f32x4;
typedef __attribute__((ext_vector_type(8))) short s16x8;
typedef __attribute__((ext_vector_type(8))) unsigned short u16x8;
typedef __attribute__((ext_vector_type(4))) unsigned short u16x4;

__device__ __forceinline__ unsigned short f2bf(float f) {
  union { float f; uint32_t u; } x; x.f = f;
  uint32_t u = x.u;
  u += 0x7fffu + ((u >> 16) & 1u);   // round-to-nearest-even
  return (unsigned short)(u >> 16);
}

// ---------- Fused prep kernel: weff blocks (bid<8192) + cast grid-stride ----------
// weff is L2/latency-bound, cast is HBM-BW-bound -> they co-schedule on the CUs.
constexpr int kWeffBlocks = kNAdapt * (kDin / 64) * (kDout / 64);   // 8192
constexpr int kCastBlocks = 2048;   // grid-stride: 2048*256*8 = 4.19M el/pass, 8 passes

__global__ __launch_bounds__(256) void prep_kernel(
    const float* __restrict__ h, unsigned short* __restrict__ hout,
    const float* __restrict__ W, const float* __restrict__ la,
    const float* __restrict__ lb, unsigned short* __restrict__ weff) {
  __shared__ float Wt[64][68];
  __shared__ float At[64][20];
  __shared__ float Bt[16][68];
  int bid = blockIdx.x;
  int t = threadIdx.x;
  if (bid >= kWeffBlocks) {
    // ---- cast path: h f32 -> bf16, 8 el/thread, grid-stride ----
    int cb = bid - kWeffBlocks;
    size_t base = (size_t)cb * 256 + t;
    constexpr size_t stride = (size_t)kCastBlocks * 256;
    constexpr size_t total8 = (size_t)kM * kDin / 8;   // 4,194,304
#pragma unroll
    for (int p = 0; p < 8; ++p) {
      size_t i = base + p * stride;
      if (i < total8) {
        const f32x4* src = reinterpret_cast<const f32x4*>(h) + i * 2;
        f32x4 v0 = src[0], v1 = src[1];
        u16x8 r;
        r[0] = f2bf(v0[0]); r[1] = f2bf(v0[1]); r[2] = f2bf(v0[2]); r[3] = f2bf(v0[3]);
        r[4] = f2bf(v1[0]); r[5] = f2bf(v1[1]); r[6] = f2bf(v1[2]); r[7] = f2bf(v1[3]);
        *reinterpret_cast<u16x8*>(hout + i * 8) = r;
      }
    }
    return;
  }
  // ---- weff path (R2 kernel, verified) ----
  int e = bid & 7;
  int rem = bid >> 3;
  int dt = rem >> 6;
  int ot = rem & 63;
  int d0 = dt * 64, o0 = ot * 64;
  {
    int r = t >> 4;
    int c = (t & 15) * 4;
    const float* wp = W + (size_t)(d0 + r) * kDout + o0 + c;
#pragma unroll
    for (int p = 0; p < 4; ++p) {
      f32x4 v = *reinterpret_cast<const f32x4*>(wp + (size_t)p * 16 * kDout);
      *reinterpret_cast<f32x4*>(&Wt[p * 16 + r][c]) = v;
    }
  }
  {
    int d = t >> 2, r4 = (t & 3) * 4;
    f32x4 v = *reinterpret_cast<const f32x4*>(la + ((size_t)e * kDin + d0 + d) * kRank + r4);
    *reinterpret_cast<f32x4*>(&At[d][r4]) = v;
  }
  {
    int r = t >> 4, c = (t & 15) * 4;
    f32x4 v = *reinterpret_cast<const f32x4*>(lb + ((size_t)e * kRank + r) * kDout + o0 + c);
    *reinterpret_cast<f32x4*>(&Bt[r][c]) = v;
  }
  __syncthreads();
  int ol_base = t >> 4;
  int dl = (t & 15) * 4;
  f32x4 areg[4][4];
#pragma unroll
  for (int j = 0; j < 4; ++j)
#pragma unroll
    for (int q = 0; q < 4; ++q)
      areg[j][q] = *reinterpret_cast<const f32x4*>(&At[dl + j][q * 4]);
#pragma unroll
  for (int p = 0; p < 4; ++p) {
    int ol = p * 16 + ol_base;
    float bv[kRank];
#pragma unroll
    for (int r = 0; r < kRank; ++r) bv[r] = Bt[r][ol];
    u16x4 r4;
#pragma unroll
    for (int j = 0; j < 4; ++j) {
      float acc = 0.f;
#pragma unroll
      for (int q = 0; q < 4; ++q)
        acc += areg[j][q][0] * bv[q * 4 + 0] + areg[j][q][1] * bv[q * 4 + 1] +
               areg[j][q][2] * bv[q * 4 + 2] + areg[j][q][3] * bv[q * 4 + 3];
      r4[j] = f2bf(Wt[dl + j][ol] + kScale * acc);
    }
    *reinterpret_cast<u16x4*>(weff + ((size_t)e * kDout + o0 + ol) * kDin + d0 + dl) = r4;
  }
}

// ---------- GEMM: 256x256, single barrier per K-tile, A tribuf + B dbuf ----------
// Per kt: VMC(4) -> s_barrier -> STG_B(kt+1) -> {24 ds_read + 64 MFMA, no
// fences} -> STG_A(kt+2). Write-safety by rotation depth (slot last read at
// kt-1; reads retired at barrier since MFMA issue requires lgkmcnt waits).
constexpr int BM = 256, BN = 256, BK = 64;
constexpr int MT2 = kM / BM;      // 128
constexpr int NT2 = kDout / BN;   // 16
constexpr int NWG2 = MT2 * NT2;   // 2048

__device__ __forceinline__ void gload16(const unsigned short* g, unsigned short* l) {
  __builtin_amdgcn_global_load_lds((const __attribute__((address_space(1))) void*)g,
                                   (__attribute__((address_space(3))) void*)l, 16, 0, 0);
}

// LDS elem layout: A slot s in [0,3): s*16384 + instr*4096 + t*8
//                  B slot s in [0,2): 49152 + s*16384 + instr*4096 + t*8
// logical (row r, elem c) lives at r*64 + (c ^ ((r&7)<<3)); source pre-swizzled.
#define STG_A(s, kk) do { \
  gload16(gA + (size_t)0 * kDin + (kk) * 64, ldst + (s) * 16384); \
  gload16(gA + (size_t)64 * kDin + (kk) * 64, ldst + (s) * 16384 + 4096); \
  gload16(gA + (size_t)128 * kDin + (kk) * 64, ldst + (s) * 16384 + 8192); \
  gload16(gA + (size_t)192 * kDin + (kk) * 64, ldst + (s) * 16384 + 12288); \
} while (0)
#define STG_B(s, kk) do { \
  gload16(gB + (size_t)0 * kDin + (kk) * 64, ldst + 49152 + (s) * 16384); \
  gload16(gB + (size_t)64 * kDin + (kk) * 64, ldst + 49152 + (s) * 16384 + 4096); \
  gload16(gB + (size_t)128 * kDin + (kk) * 64, ldst + 49152 + (s) * 16384 + 8192); \
  gload16(gB + (size_t)192 * kDin + (kk) * 64, ldst + 49152 + (s) * 16384 + 12288); \
} while (0)

#define RD_A(mh, s) do { _Pragma("unroll") for (int ii = 0; ii < 4; ++ii) { \
  a[ii][0] = *(const s16x8*)&lds[(s) * 16384 + aRow + ((mh) * 4 + ii) * 1024 + e0]; \
  a[ii][1] = *(const s16x8*)&lds[(s) * 16384 + aRow + ((mh) * 4 + ii) * 1024 + e1]; } } while (0)
#define RD_B(nh, breg, s) do { _Pragma("unroll") for (int jj = 0; jj < 2; ++jj) { \
  breg[jj][0] = *(const s16x8*)&lds[49152 + (s) * 16384 + bRow + ((nh) * 2 + jj) * 1024 + e0]; \
  breg[jj][1] = *(const s16x8*)&lds[49152 + (s) * 16384 + bRow + ((nh) * 2 + jj) * 1024 + e1]; } } while (0)

#define MMQ(mh, nh, breg) do { \
  _Pragma("unroll") for (int ii = 0; ii < 4; ++ii) \
  _Pragma("unroll") for (int jj = 0; jj < 2; ++jj) { \
    acc[(mh) * 4 + ii][(nh) * 2 + jj] = __builtin_amdgcn_mfma_f32_16x16x32_bf16( \
        a[ii][0], breg[jj][0], acc[(mh) * 4 + ii][(nh) * 2 + jj], 0, 0, 0); \
    acc[(mh) * 4 + ii][(nh) * 2 + jj] = __builtin_amdgcn_mfma_f32_16x16x32_bf16( \
        a[ii][1], breg[jj][1], acc[(mh) * 4 + ii][(nh) * 2 + jj], 0, 0, 0); } \
} while (0)

#define VMC(n) asm volatile("s_waitcnt vmcnt(" #n ")" ::: "memory")

__global__ __launch_bounds__(512, 2) void gemm256_kernel(
    const unsigned short* __restrict__ Ab,    // [M][K] bf16
    const unsigned short* __restrict__ Weff,  // [NA][N][K] bf16
    const float* __restrict__ bias,
    const int* __restrict__ aids,
    float* __restrict__ out) {
  __shared__ unsigned short lds[81920];   // 160 KiB: A[3] + B[2] slots
  int bid = blockIdx.x;
  int swz = (bid & 7) * (NWG2 / 8) + (bid >> 3);   // XCD-aware, bijective
  int mt = swz >> 4, nt = swz & 15;
  int aid = aids[mt >> 2];   // BM=256 divides S=1024: one sample per M-tile
  const unsigned short* Aptr = Ab + (size_t)mt * BM * kDin;
  const unsigned short* Bptr = Weff + ((size_t)aid * kDout + (size_t)nt * BN) * kDin;

  int t = threadIdx.x;
  int l = t & 63;
  int w = t >> 6;
  int wm = w >> 2;   // 0..1 (M)
  int wn = w & 3;    // 0..3 (N)

  // staging: thread t covers row t>>3 (per 64-row chunk), 16B col (t&7);
  // global source col pre-swizzled so LDS stays linear (rule #21)
  int srcColEl = ((t & 7) * 8) ^ (((t >> 3) & 7) << 3);
  const unsigned short* gA = Aptr + (size_t)(t >> 3) * kDin + srcColEl;
  const unsigned short* gB = Bptr + (size_t)(t >> 3) * kDin + srcColEl;
  unsigned short* ldst = lds + t * 8;

  // fragment-read addressing (element units)
  int xmEl = (l & 7) << 3;
  int e0 = (((l >> 4) * 8) ^ xmEl);
  int e1 = e0 ^ 32;
  int aRow = (wm * 128 + (l & 15)) * 64;
  int bRow = (wn * 64 + (l & 15)) * 64;

  f32x4 acc[8][4];
#pragma unroll
  for (int m = 0; m < 8; ++m)
#pragma unroll
    for (int n = 0; n < 4; ++n) acc[m][n] = f32x4{0.f, 0.f, 0.f, 0.f};
  s16x8 a[4][2], b0[2][2], b1[2][2];

  // prologue FIFO: [A0(4), B0(4), A1(4)]
  STG_A(0, 0); STG_B(0, 0); STG_A(1, 1);

#pragma unroll
  for (int kt = 0; kt < 16; ++kt) {
    const int sa = kt % 3;          // A slot being read
    const int sb = kt & 1;          // B slot being read
    if (kt < 15) { VMC(4); } else { VMC(0); }   // force L(kt); allow A(kt+1)
    __builtin_amdgcn_s_barrier();
    __builtin_amdgcn_sched_barrier(0);
    if (kt < 15) STG_B((kt + 1) & 1, kt + 1);   // slot last read kt-1: safe
    // ---- body: no fences; compiler interleaves ds_read/MFMA (lgkmcnt per-use)
    RD_A(0, sa);
    RD_B(0, b0, sb); RD_B(1, b1, sb);
    MMQ(0, 0, b0); MMQ(0, 1, b1);
    RD_A(1, sa);
    MMQ(1, 0, b0); MMQ(1, 1, b1);
    if (kt < 14) STG_A((kt + 2) % 3, kt + 2);   // slot last read kt-1: safe
  }

  // epilogue: C/D layout col = lane&15, row = (lane>>4)*4 + reg
  size_t row0 = (size_t)mt * BM + wm * 128 + (l >> 4) * 4;
  int col0 = nt * BN + wn * 64 + (l & 15);
#pragma unroll
  for (int nf = 0; nf < 4; ++nf) {
    float bv = bias[col0 + nf * 16];
#pragma unroll
    for (int mf = 0; mf < 8; ++mf) {
#pragma unroll
      for (int j = 0; j < 4; ++j)
        out[(row0 + mf * 16 + j) * kDout + col0 + nf * 16] = acc[mf][nf][j] + bv;
    }
  }
}

extern "C" void kernel_launch(void* const* d_in, const int* in_sizes, int n_in,
                              void* d_out, int out_size, void* d_ws, size_t ws_size,
                              hipStream_t stream) {
  const float* h    = (const float*)d_in[0];   // [32,1024,1024] f32
  const int*   aids = (const int*)d_in[1];     // [32] i32
  const float* W    = (const float*)d_in[2];   // [1024,4096] f32
  const float* bias = (const float*)d_in[3];   // [4096] f32
  const float* la   = (const float*)d_in[4];   // [8,1024,16] f32
  const float* lb   = (const float*)d_in[5];   // [8,16,4096] f32
  float* out = (float*)d_out;                  // [32,1024,4096] f32

  unsigned short* Abf  = (unsigned short*)d_ws;
  unsigned short* Weff = Abf + (size_t)kM * kDin;

  prep_kernel<<<kWeffBlocks + kCastBlocks, 256, 0, stream>>>(h, Abf, W, la, lb, Weff);
  gemm256_kernel<<<NWG2, 512, 0, stream>>>(Abf, Weff, bias, aids, out);
}